// Round 2
// baseline (34.977 us; speedup 1.0000x reference)
//
#include <hip/hip_runtime.h>
#include <math.h>

#define E_ALL  4100
#define NENT_C 4096
#define DIM    128
#define NBLK   33
#define NTHR   1024
#define RPB    128      // rows per block = 16 waves * 8 rows

// Fused FALCON loss:
//   u[j] = e_all[j]·w1, v[j] = e_all[j]·w2          (phase 1, all blocks)
//   vmax = max_j v[j]                                (last block)
//   maxfs[b] = max_j sigmoid(u_j + sr_b + b0 + vmax) * sigmoid(v_j + sc_b + b0)
//            = 1 / min_j (1+e^{-(u_j+A_b)})(1+e^{-(v_j+C_b)})
//   loss = mean_b -log(1 - maxfs[b] + 1e-10)
__global__ __launch_bounds__(NTHR)
void falcon_fused(const int* __restrict__ x,
                  const float* __restrict__ anon,
                  const float* __restrict__ c_table,
                  const float* __restrict__ r_table,
                  const float* __restrict__ e_table,
                  const float* __restrict__ fc_w,
                  const float* __restrict__ fc_b,
                  float* __restrict__ u,
                  float* __restrict__ v,
                  float* __restrict__ pbv,
                  unsigned int* __restrict__ cnt,
                  float* __restrict__ out)
{
    const int tid  = threadIdx.x;
    const int lane = tid & 63;
    const int wave = tid >> 6;   // 0..15

    __shared__ float s_wv[16];
    __shared__ float s_vmax, s_sr[8], s_sc[8];
    __shared__ float s_q[8][16];
    __shared__ unsigned s_old;

    const float w1a = fc_w[2*lane];
    const float w1b = fc_w[2*lane + 1];
    const float w2a = fc_w[DIM + 2*lane];
    const float w2b = fc_w[DIM + 2*lane + 1];

    // ---- Phase 1: this block's 128 rows of u, v ----
    const int jbase = blockIdx.x * RPB + wave * 8;
    float2 e[8];
#pragma unroll
    for (int r = 0; r < 8; ++r) {
        int j  = jbase + r;
        int jc = (j < E_ALL) ? j : 0;
        const float* row = (jc < NENT_C) ? (e_table + (size_t)jc * DIM)
                                         : (anon + (size_t)(jc - NENT_C) * DIM);
        e[r] = *reinterpret_cast<const float2*>(row + 2*lane);
    }
    float wvmax = -INFINITY;
#pragma unroll
    for (int r = 0; r < 8; ++r) {
        const int j = jbase + r;
        float pu = fmaf(e[r].x, w1a, e[r].y * w1b);
        float pv = fmaf(e[r].x, w2a, e[r].y * w2b);
#pragma unroll
        for (int o = 32; o; o >>= 1) {
            pu += __shfl_xor(pu, o);
            pv += __shfl_xor(pv, o);
        }
        if (lane == 0 && j < E_ALL) {
            u[j] = pu;
            v[j] = pv;
            wvmax = fmaxf(wvmax, pv);
        }
    }
    if (lane == 0) s_wv[wave] = wvmax;
    __syncthreads();
    if (tid == 0) {
        float bm = -INFINITY;
        for (int w = 0; w < 16; ++w) bm = fmaxf(bm, s_wv[w]);
        pbv[blockIdx.x] = bm;
    }
    __threadfence();          // release this block's u/v/pbv stores device-wide
    __syncthreads();
    if (tid == 0) s_old = atomicAdd(cnt, 1u);
    __syncthreads();
    if (s_old != NBLK - 1) return;

    // ---- Last block only: finish the reduction ----
    __threadfence();          // acquire other blocks' stores

    if (wave == 0) {          // vmax over the 33 per-block partials
        float vm = (lane < NBLK) ? pbv[lane] : -INFINITY;
#pragma unroll
        for (int o = 32; o; o >>= 1) vm = fmaxf(vm, __shfl_xor(vm, o));
        if (lane == 0) s_vmax = vm;
    }
    // sr[b] = r_table[x[b,0]]·w1 (waves 0-7), sc[b] = c_table[x[b,1]]·w1 (waves 8-15)
    if (wave < 8) {
        const int ri = x[2*wave];
        const float2 rr = *reinterpret_cast<const float2*>(r_table + (size_t)ri * DIM + 2*lane);
        float p = fmaf(rr.x, w1a, rr.y * w1b);
#pragma unroll
        for (int o = 32; o; o >>= 1) p += __shfl_xor(p, o);
        if (lane == 0) s_sr[wave] = p;
    } else {
        const int b  = wave - 8;
        const int ci = x[2*b + 1];
        const float2 cc = *reinterpret_cast<const float2*>(c_table + (size_t)ci * DIM + 2*lane);
        float p = fmaf(cc.x, w1a, cc.y * w1b);
#pragma unroll
        for (int o = 32; o; o >>= 1) p += __shfl_xor(p, o);
        if (lane == 0) s_sc[b] = p;
    }
    __syncthreads();

    const float b0   = fc_b[0];
    const float vmax = s_vmax;
    float A[8], C[8], q[8];
#pragma unroll
    for (int b = 0; b < 8; ++b) {
        A[b] = s_sr[b] + b0 + vmax;
        C[b] = s_sc[b] + b0;
        q[b] = INFINITY;
    }

    for (int j = tid; j < E_ALL; j += NTHR) {
        const float uj = u[j];
        const float vj = v[j];
#pragma unroll
        for (int b = 0; b < 8; ++b) {
            const float e1 = __expf(-(uj + A[b]));
            const float e2 = __expf(-(vj + C[b]));
            q[b] = fminf(q[b], (1.0f + e1) * (1.0f + e2));
        }
    }

#pragma unroll
    for (int b = 0; b < 8; ++b) {
        float t = q[b];
#pragma unroll
        for (int o = 32; o; o >>= 1) t = fminf(t, __shfl_xor(t, o));
        if (lane == 0) s_q[b][wave] = t;
    }
    __syncthreads();
    if (tid < 8) {
        float qm = INFINITY;
        for (int w = 0; w < 16; ++w) qm = fminf(qm, s_q[tid][w]);
        const float fs = 1.0f / qm;                       // maxfs[b], full-precision div
        float t = -logf(1.0f - fs + 1e-10f);
#pragma unroll
        for (int o = 4; o; o >>= 1) t += __shfl_xor(t, o); // sum over lanes 0..7
        if (tid == 0) out[0] = t * 0.125f;
    }
}

extern "C" void kernel_launch(void* const* d_in, const int* in_sizes, int n_in,
                              void* d_out, int out_size, void* d_ws, size_t ws_size,
                              hipStream_t stream) {
    const int*   x        = (const int*)d_in[0];
    const float* anon     = (const float*)d_in[1];
    const float* c_table  = (const float*)d_in[2];
    const float* r_table  = (const float*)d_in[3];
    const float* e_table  = (const float*)d_in[4];
    const float* fc_w     = (const float*)d_in[5];
    const float* fc_b     = (const float*)d_in[6];
    float* out = (float*)d_out;

    float* u   = (float*)d_ws;        // 4224 floats (rounded up from 4100)
    float* v   = u + 4224;            // 4224 floats
    float* pbv = v + 4224;            // 33 floats (pad to 64)
    unsigned int* cnt = (unsigned int*)(pbv + 64);

    hipMemsetAsync(cnt, 0, sizeof(unsigned int), stream);  // capture-safe memset node
    falcon_fused<<<NBLK, NTHR, 0, stream>>>(x, anon, c_table, r_table, e_table,
                                            fc_w, fc_b, u, v, pbv, cnt, out);
}

// Round 3
// 17.255 us; speedup vs baseline: 2.0271x; 2.0271x over previous
//
#include <hip/hip_runtime.h>
#include <math.h>

#define E_ALL  4100
#define NENT_C 4096
#define DIM    128
#define NBLK_UV 129     // ceil(4100 / 32)

// Kernel 1: u[j] = e_all[j]·w1, v[j] = e_all[j]·w2, pbv[blk] = max_j(in blk) v[j]
// 4 waves/block, one wave per row, 8 rows/wave, float2 per lane.
__global__ __launch_bounds__(256)
void k_uv(const float* __restrict__ e_table,
          const float* __restrict__ anon,
          const float* __restrict__ fc_w,
          float* __restrict__ u, float* __restrict__ v,
          float* __restrict__ pbv)
{
    const int lane = threadIdx.x & 63;
    const int wave = threadIdx.x >> 6;   // 0..3
    __shared__ float s_wv[4];

    const float w1a = fc_w[2*lane];
    const float w1b = fc_w[2*lane + 1];
    const float w2a = fc_w[DIM + 2*lane];
    const float w2b = fc_w[DIM + 2*lane + 1];

    const int jbase = blockIdx.x * 32 + wave * 8;
    float wvmax = -INFINITY;             // tracked on lane 0 only
#pragma unroll
    for (int r = 0; r < 8; ++r) {
        const int j = jbase + r;
        if (j >= E_ALL) break;           // uniform across the wave
        const float* row = (j < NENT_C) ? (e_table + (size_t)j * DIM)
                                        : (anon + (size_t)(j - NENT_C) * DIM);
        const float2 e = *reinterpret_cast<const float2*>(row + 2*lane);
        float pu = fmaf(e.x, w1a, e.y * w1b);
        float pv = fmaf(e.x, w2a, e.y * w2b);
#pragma unroll
        for (int o = 32; o; o >>= 1) {
            pu += __shfl_xor(pu, o);
            pv += __shfl_xor(pv, o);
        }
        if (lane == 0) {
            u[j] = pu;
            v[j] = pv;
            wvmax = fmaxf(wvmax, pv);
        }
    }
    if (lane == 0) s_wv[wave] = wvmax;
    __syncthreads();
    if (threadIdx.x == 0)
        pbv[blockIdx.x] = fmaxf(fmaxf(s_wv[0], s_wv[1]), fmaxf(s_wv[2], s_wv[3]));
}

// Kernel 2: single block, 1024 threads (16 waves).
//   maxfs[b] = 1 / min_j (1+e^{-(u_j+A_b)})(1+e^{-(v_j+C_b)})
//   loss = mean_b -log(1 - maxfs[b] + 1e-10)
__global__ __launch_bounds__(1024)
void k_final(const float* __restrict__ u, const float* __restrict__ v,
             const float* __restrict__ pbv,
             const int* __restrict__ x,
             const float* __restrict__ c_table,
             const float* __restrict__ r_table,
             const float* __restrict__ fc_w,
             const float* __restrict__ fc_b,
             float* __restrict__ out)
{
    __shared__ float s_vmax, s_sr[8], s_sc[8];
    __shared__ float s_q[8][16];
    const int tid  = threadIdx.x;
    const int lane = tid & 63;
    const int wave = tid >> 6;           // 0..15

    // sr[b] (waves 0-7) and sc[b] (waves 8-15): 64-lane float2 dots
    {
        const float w1a = fc_w[2*lane];
        const float w1b = fc_w[2*lane + 1];
        const float* src;
        if (wave < 8) src = r_table + (size_t)x[2*wave] * DIM;
        else          src = c_table + (size_t)x[2*(wave - 8) + 1] * DIM;
        const float2 t = *reinterpret_cast<const float2*>(src + 2*lane);
        float p = fmaf(t.x, w1a, t.y * w1b);
#pragma unroll
        for (int o = 32; o; o >>= 1) p += __shfl_xor(p, o);
        if (lane == 0) {
            if (wave < 8) s_sr[wave] = p;
            else          s_sc[wave - 8] = p;
        }
    }
    // vmax over the 129 per-block partials (wave 0)
    if (wave == 0) {
        float vm = -INFINITY;
        for (int i = lane; i < NBLK_UV; i += 64) vm = fmaxf(vm, pbv[i]);
#pragma unroll
        for (int o = 32; o; o >>= 1) vm = fmaxf(vm, __shfl_xor(vm, o));
        if (lane == 0) s_vmax = vm;
    }
    __syncthreads();

    const float b0   = fc_b[0];
    const float vmax = s_vmax;
    float A[8], C[8], q[8];
#pragma unroll
    for (int b = 0; b < 8; ++b) {
        A[b] = s_sr[b] + b0 + vmax;
        C[b] = s_sc[b] + b0;
        q[b] = INFINITY;
    }

    for (int j = tid; j < E_ALL; j += 1024) {
        const float uj = u[j];
        const float vj = v[j];
#pragma unroll
        for (int b = 0; b < 8; ++b) {
            const float e1 = __expf(-(uj + A[b]));
            const float e2 = __expf(-(vj + C[b]));
            q[b] = fminf(q[b], (1.0f + e1) * (1.0f + e2));
        }
    }

#pragma unroll
    for (int b = 0; b < 8; ++b) {
        float t = q[b];
#pragma unroll
        for (int o = 32; o; o >>= 1) t = fminf(t, __shfl_xor(t, o));
        if (lane == 0) s_q[b][wave] = t;
    }
    __syncthreads();
    if (tid < 8) {
        float qm = INFINITY;
#pragma unroll
        for (int w = 0; w < 16; ++w) qm = fminf(qm, s_q[tid][w]);
        const float fs = 1.0f / qm;                        // maxfs[b]
        float t = -logf(1.0f - fs + 1e-10f);
#pragma unroll
        for (int o = 4; o; o >>= 1) t += __shfl_xor(t, o); // sum lanes 0..7
        if (tid == 0) out[0] = t * 0.125f;
    }
}

extern "C" void kernel_launch(void* const* d_in, const int* in_sizes, int n_in,
                              void* d_out, int out_size, void* d_ws, size_t ws_size,
                              hipStream_t stream) {
    const int*   x        = (const int*)d_in[0];
    const float* anon     = (const float*)d_in[1];
    const float* c_table  = (const float*)d_in[2];
    const float* r_table  = (const float*)d_in[3];
    const float* e_table  = (const float*)d_in[4];
    const float* fc_w     = (const float*)d_in[5];
    const float* fc_b     = (const float*)d_in[6];
    float* out = (float*)d_out;

    float* u   = (float*)d_ws;        // 4224 floats
    float* v   = u + 4224;            // 4224 floats
    float* pbv = v + 4224;            // 129 floats

    k_uv<<<NBLK_UV, 256, 0, stream>>>(e_table, anon, fc_w, u, v, pbv);
    k_final<<<1, 1024, 0, stream>>>(u, v, pbv, x, c_table, r_table, fc_w, fc_b, out);
}

// Round 4
// 14.817 us; speedup vs baseline: 2.3606x; 1.1645x over previous
//
#include <hip/hip_runtime.h>
#include <math.h>

#define E_ALL   4100
#define NENT_C  4096
#define DIM     128
#define NBLK_UV 129     // ceil(4100 / 32), 32 rows per block

// Kernel 1: uv[j] = (e_all[j]·w1, e_all[j]·w2); pbv[blk] = max over block's j of v.
// 4 waves/block; each wave: 8 rows as 4 iterations × 2 rows (32-lane halves),
// float4 per lane, all loads prefetched before the reduce.
__global__ __launch_bounds__(256)
void k_uv(const float* __restrict__ e_table,
          const float* __restrict__ anon,
          const float* __restrict__ fc_w,
          float2* __restrict__ uv,
          float* __restrict__ pbv)
{
    const int tid  = threadIdx.x;
    const int lane = tid & 63;
    const int half = lane >> 5;          // 0: even row, 1: odd row
    const int l32  = lane & 31;
    const int wave = tid >> 6;           // 0..3
    __shared__ float s_wv[8];

    const float4 w1q = *reinterpret_cast<const float4*>(fc_w + 4*l32);
    const float4 w2q = *reinterpret_cast<const float4*>(fc_w + DIM + 4*l32);

    const int jbase = blockIdx.x * 32 + wave * 8;

    // prefetch all 4 row-pairs (clamped; writes predicated later)
    float4 e[4];
#pragma unroll
    for (int i = 0; i < 4; ++i) {
        int j  = jbase + 2*i + half;
        int jc = (j < E_ALL) ? j : (E_ALL - 1);
        const float* row = (jc < NENT_C) ? (e_table + (size_t)jc * DIM)
                                         : (anon + (size_t)(jc - NENT_C) * DIM);
        e[i] = *reinterpret_cast<const float4*>(row + 4*l32);
    }

    float wvmax = -INFINITY;             // meaningful on lanes 0 and 32
#pragma unroll
    for (int i = 0; i < 4; ++i) {
        const int j = jbase + 2*i + half;
        float pu = fmaf(e[i].x, w1q.x, fmaf(e[i].y, w1q.y, fmaf(e[i].z, w1q.z, e[i].w * w1q.w)));
        float pv = fmaf(e[i].x, w2q.x, fmaf(e[i].y, w2q.y, fmaf(e[i].z, w2q.z, e[i].w * w2q.w)));
#pragma unroll
        for (int o = 16; o; o >>= 1) {   // reduce within each 32-lane half
            pu += __shfl_xor(pu, o);
            pv += __shfl_xor(pv, o);
        }
        if (l32 == 0 && j < E_ALL) {
            uv[j] = make_float2(pu, pv);
            wvmax = fmaxf(wvmax, pv);
        }
    }
    if (l32 == 0) s_wv[wave * 2 + half] = wvmax;
    __syncthreads();
    if (tid == 0) {
        float bm = s_wv[0];
#pragma unroll
        for (int k = 1; k < 8; ++k) bm = fmaxf(bm, s_wv[k]);
        pbv[blockIdx.x] = bm;
    }
}

// Kernel 2: single block, 1024 threads.
//   maxfs[b] = 1 / min_j (1 + e^{-u_j}·kb[b]) (1 + e^{-v_j}·mb[b])
//     with kb[b] = e^{-A_b}, mb[b] = e^{-C_b},
//     A_b = sr_b + b0 + vmax, C_b = sc_b + b0.
//   loss = mean_b -log(1 - maxfs[b] + 1e-10)
__global__ __launch_bounds__(1024)
void k_final(const float2* __restrict__ uv, const float* __restrict__ pbv,
             const int* __restrict__ x,
             const float* __restrict__ c_table,
             const float* __restrict__ r_table,
             const float* __restrict__ fc_w,
             const float* __restrict__ fc_b,
             float* __restrict__ out)
{
    __shared__ float s_vmax, s_sr[8], s_sc[8];
    __shared__ float s_q[8][16];
    const int tid  = threadIdx.x;
    const int lane = tid & 63;
    const int wave = tid >> 6;           // 0..15

    // ---- early prefetch of the uv sweep (latency hidden under the prologue) ----
    const float2 p0 = uv[tid];
    const float2 p1 = uv[tid + 1024];
    const float2 p2 = uv[tid + 2048];
    const float2 p3 = uv[tid + 3072];
    // tail: only tids 0..3 have a 5th element; others re-read their own j
    // (duplicate j is harmless — min is idempotent)
    const float2 p4 = uv[(tid < 4) ? tid + 4096 : tid];

    // ---- prologue: sr[b] (waves 0-7), sc[b] (waves 8-15) ----
    {
        const float w1a = fc_w[2*lane];
        const float w1b = fc_w[2*lane + 1];
        const float* src = (wave < 8) ? (r_table + (size_t)x[2*wave] * DIM)
                                      : (c_table + (size_t)x[2*(wave - 8) + 1] * DIM);
        const float2 t = *reinterpret_cast<const float2*>(src + 2*lane);
        float p = fmaf(t.x, w1a, t.y * w1b);
#pragma unroll
        for (int o = 32; o; o >>= 1) p += __shfl_xor(p, o);
        if (lane == 0) {
            if (wave < 8) s_sr[wave] = p;
            else          s_sc[wave - 8] = p;
        }
    }
    // vmax over 129 per-block partials (wave 0)
    if (wave == 0) {
        const float a = pbv[lane];
        const float b = pbv[lane + 64];
        const float c = pbv[128];        // same address all lanes -> broadcast
        float vm = fmaxf(fmaxf(a, b), c);
#pragma unroll
        for (int o = 32; o; o >>= 1) vm = fmaxf(vm, __shfl_xor(vm, o));
        if (lane == 0) s_vmax = vm;
    }
    __syncthreads();

    const float b0   = fc_b[0];
    const float vmax = s_vmax;
    float kb[8], mb[8], q[8];
#pragma unroll
    for (int b = 0; b < 8; ++b) {
        kb[b] = __expf(-(s_sr[b] + b0 + vmax));
        mb[b] = __expf(-(s_sc[b] + b0));
        q[b]  = INFINITY;
    }

#define PROC(P)                                                   \
    {                                                             \
        const float eu = __expf(-(P).x);                          \
        const float ev = __expf(-(P).y);                          \
        _Pragma("unroll")                                         \
        for (int b = 0; b < 8; ++b) {                             \
            const float t1 = fmaf(eu, kb[b], 1.0f);               \
            const float t2 = fmaf(ev, mb[b], 1.0f);               \
            q[b] = fminf(q[b], t1 * t2);                          \
        }                                                         \
    }
    PROC(p0); PROC(p1); PROC(p2); PROC(p3); PROC(p4);
#undef PROC

#pragma unroll
    for (int b = 0; b < 8; ++b) {
        float t = q[b];
#pragma unroll
        for (int o = 32; o; o >>= 1) t = fminf(t, __shfl_xor(t, o));
        if (lane == 0) s_q[b][wave] = t;
    }
    __syncthreads();
    if (tid < 8) {
        float qm = INFINITY;
#pragma unroll
        for (int w = 0; w < 16; ++w) qm = fminf(qm, s_q[tid][w]);
        const float fs = 1.0f / qm;                         // maxfs[b]
        float t = -logf(1.0f - fs + 1e-10f);
#pragma unroll
        for (int o = 4; o; o >>= 1) t += __shfl_xor(t, o);  // sum lanes 0..7
        if (tid == 0) out[0] = t * 0.125f;
    }
}

extern "C" void kernel_launch(void* const* d_in, const int* in_sizes, int n_in,
                              void* d_out, int out_size, void* d_ws, size_t ws_size,
                              hipStream_t stream) {
    const int*   x        = (const int*)d_in[0];
    const float* anon     = (const float*)d_in[1];
    const float* c_table  = (const float*)d_in[2];
    const float* r_table  = (const float*)d_in[3];
    const float* e_table  = (const float*)d_in[4];
    const float* fc_w     = (const float*)d_in[5];
    const float* fc_b     = (const float*)d_in[6];
    float* out = (float*)d_out;

    float2* uv  = (float2*)d_ws;                 // 4100 float2 (32800 B)
    float*  pbv = (float*)d_ws + 8320;           // 129 floats

    k_uv<<<NBLK_UV, 256, 0, stream>>>(e_table, anon, fc_w, uv, pbv);
    k_final<<<1, 1024, 0, stream>>>(uv, pbv, x, c_table, r_table, fc_w, fc_b, out);
}